// Round 4
// baseline (7528.274 us; speedup 1.0000x reference)
//
#include <hip/hip_runtime.h>
#include <math.h>

#define N_NODES 50000
#define N_EDGES 500000
#define N_TRIP  1000000
#define DIM     128
#define NBF     20
#define CUTOFF  5.0f

#define BM   128
#define BK   32
#define NTHR 256

__device__ __forceinline__ float sigmoidf_(float x){ return 1.0f/(1.0f+expf(-x)); }
__device__ __forceinline__ float siluf_(float x){ return x/(1.0f+expf(-x)); }
__device__ __forceinline__ float n2nf_(float x){ return __builtin_isfinite(x) ? x : 0.0f; }

// ---- shared GEMM microkernel: 128x128 tile, 256 thr, 8x8 microtile ----
// fp32 VALU GEMM (no fp32-input MFMA on CDNA4). ~157 TF chip ceiling.
__device__ __forceinline__ void tile_mac(float As[][132], float Bs[][DIM],
                                         int ty8, int tx8, float acc[8][8]) {
#pragma unroll
  for (int k = 0; k < BK; ++k) {
    float a[8], b[8];
    *(float4*)&a[0] = *(const float4*)&As[k][ty8];
    *(float4*)&a[4] = *(const float4*)&As[k][ty8+4];
    *(float4*)&b[0] = *(const float4*)&Bs[k][tx8];
    *(float4*)&b[4] = *(const float4*)&Bs[k][tx8+4];
#pragma unroll
    for (int i = 0; i < 8; ++i)
#pragma unroll
      for (int j = 0; j < 8; ++j)
        acc[i][j] = fmaf(a[i], b[j], acc[i][j]);
  }
}

// load 32 rows of a K x 128 weight matrix into Bs (rows >= Kw zeroed)
__device__ __forceinline__ void load_W(const float* __restrict__ W, int kt, int Kw,
                                       float Bs[][DIM], int t) {
  int row = t >> 5;          // 0..7
  int col = (t & 31) << 2;   // 0..124
#pragma unroll
  for (int p = 0; p < 4; ++p) {
    int k = kt + p*8 + row;
    float4 v = make_float4(0.f,0.f,0.f,0.f);
    if (k < Kw) v = *(const float4*)&W[(size_t)k*DIM + col];
    *(float4*)&Bs[p*8+row][col] = v;
  }
}

// ---- K0: Wc = phi_W2 @ upd_W ; pb2u = phi_b2 @ upd_W ----
// Linear-algebra fold: segment_sum(m_ijk)@upd_W = segment_sum(silu(h@phiW1))@(phiW2@updW)
//                      + cnt * (phi_b2@updW). Deletes the per-triplet 128x128 GEMM.
__global__ __launch_bounds__(128) void k0_combine(
    const float* __restrict__ phiW2, const float* __restrict__ phib2,
    const float* __restrict__ updW,
    float* __restrict__ Wc, float* __restrict__ pb2u)
{
  int b = blockIdx.x, t = threadIdx.x;
  if (b < DIM) {
    float a = 0.f;
    for (int k = 0; k < DIM; ++k) a = fmaf(phiW2[b*DIM+k], updW[k*DIM+t], a);
    Wc[b*DIM+t] = a;
  } else {
    float a = 0.f;
    for (int k = 0; k < DIM; ++k) a = fmaf(phib2[k], updW[k*DIM+t], a);
    pb2u[t] = a;
  }
}

// ---- K1a: H1 = silu([nf[src], nf[dst], ef] @ edge_W1 + b1) -> outE ----
__global__ __launch_bounds__(NTHR) void k1a_edge_h1(
    const float* __restrict__ nf, const float* __restrict__ ef,
    const int* __restrict__ src, const int* __restrict__ dst,
    const float* __restrict__ W1, const float* __restrict__ b1,
    float* __restrict__ H1)
{
  __shared__ __align__(16) float As[BK][132];
  __shared__ __align__(16) float Bs[BK][DIM];
  __shared__ int s_src[BM], s_dst[BM];
  const int t = threadIdx.x;
  const int rowbase = blockIdx.x * BM;
  if (t < BM) {
    int r = min(rowbase + t, N_EDGES-1);
    s_src[t] = src[r]; s_dst[t] = dst[r];
  }
  float acc[8][8];
#pragma unroll
  for (int i=0;i<8;i++)
#pragma unroll
    for (int j=0;j<8;j++) acc[i][j]=0.f;
  const int rr = t >> 3, kk = (t & 7) << 2;
  const int ty8 = (t >> 4) << 3, tx8 = (t & 15) << 3;
  for (int kt = 0; kt < 3*DIM; kt += BK) {
    __syncthreads();
#pragma unroll
    for (int p = 0; p < 4; ++p) {
      int m = p*32 + rr;
      int c = kt + kk;
      float4 v;
      if (c < DIM)        v = *(const float4*)&nf[(size_t)s_src[m]*DIM + c];
      else if (c < 2*DIM) v = *(const float4*)&nf[(size_t)s_dst[m]*DIM + (c-DIM)];
      else { int r = min(rowbase+m, N_EDGES-1);
                          v = *(const float4*)&ef[(size_t)r*DIM + (c-2*DIM)]; }
      As[kk+0][m]=v.x; As[kk+1][m]=v.y; As[kk+2][m]=v.z; As[kk+3][m]=v.w;
    }
    load_W(W1, kt, 3*DIM, Bs, t);
    __syncthreads();
    tile_mac(As, Bs, ty8, tx8, acc);
  }
#pragma unroll
  for (int i=0;i<8;i++) {
    int r = rowbase + ty8 + i;
    if (r < N_EDGES) {
      float o[8];
#pragma unroll
      for (int j=0;j<8;j++) o[j] = siluf_(acc[i][j] + b1[tx8+j]);
      *(float4*)&H1[(size_t)r*DIM + tx8]     = *(float4*)&o[0];
      *(float4*)&H1[(size_t)r*DIM + tx8 + 4] = *(float4*)&o[4];
    }
  }
}

// ---- K1b: outE = ef + (H1@W2 + b2) * sigmoid(ef@gW + gb)  (H1 lives in outE) ----
__global__ __launch_bounds__(NTHR) void k1b_edge_out(
    const float* __restrict__ ef,
    const float* __restrict__ W2, const float* __restrict__ b2,
    const float* __restrict__ gW, const float* __restrict__ gb,
    float* __restrict__ outE)
{
  __shared__ __align__(16) float As[BK][132];
  __shared__ __align__(16) float Bs[BK][DIM];
  const int t = threadIdx.x;
  const int rowbase = blockIdx.x * BM;
  const int rr = t >> 3, kk = (t & 7) << 2;
  const int ty8 = (t >> 4) << 3, tx8 = (t & 15) << 3;
  float acc1[8][8], acc2[8][8];
#pragma unroll
  for (int i=0;i<8;i++)
#pragma unroll
    for (int j=0;j<8;j++){ acc1[i][j]=0.f; acc2[i][j]=0.f; }
  for (int kt = 0; kt < DIM; kt += BK) {     // phase 1: H1 @ W2
    __syncthreads();
#pragma unroll
    for (int p = 0; p < 4; ++p) {
      int m = p*32 + rr;
      int r = min(rowbase+m, N_EDGES-1);
      float4 v = *(const float4*)&outE[(size_t)r*DIM + kt + kk];
      As[kk+0][m]=v.x; As[kk+1][m]=v.y; As[kk+2][m]=v.z; As[kk+3][m]=v.w;
    }
    load_W(W2, kt, DIM, Bs, t);
    __syncthreads();
    tile_mac(As, Bs, ty8, tx8, acc1);
  }
  for (int kt = 0; kt < DIM; kt += BK) {     // phase 2: ef @ gW
    __syncthreads();
#pragma unroll
    for (int p = 0; p < 4; ++p) {
      int m = p*32 + rr;
      int r = min(rowbase+m, N_EDGES-1);
      float4 v = *(const float4*)&ef[(size_t)r*DIM + kt + kk];
      As[kk+0][m]=v.x; As[kk+1][m]=v.y; As[kk+2][m]=v.z; As[kk+3][m]=v.w;
    }
    load_W(gW, kt, DIM, Bs, t);
    __syncthreads();
    tile_mac(As, Bs, ty8, tx8, acc2);
  }
#pragma unroll
  for (int i=0;i<8;i++) {
    int r = rowbase + ty8 + i;
    if (r < N_EDGES) {
      float e[8];
      *(float4*)&e[0] = *(const float4*)&ef[(size_t)r*DIM + tx8];
      *(float4*)&e[4] = *(const float4*)&ef[(size_t)r*DIM + tx8 + 4];
      float o[8];
#pragma unroll
      for (int j=0;j<8;j++) {
        float ep = acc1[i][j] + b2[tx8+j];
        float g  = sigmoidf_(acc2[i][j] + gb[tx8+j]);
        o[j] = e[j] + ep * g;
      }
      *(float4*)&outE[(size_t)r*DIM + tx8]     = *(float4*)&o[0];
      *(float4*)&outE[(size_t)r*DIM + tx8 + 4] = *(float4*)&o[4];
    }
  }
}

// ---- K2b: per-triplet phi layer-1, atomic segment-sum into S ----
__global__ __launch_bounds__(NTHR) void k2b_phi(
    const float* __restrict__ ef1, const float* __restrict__ ev,
    const int* __restrict__ tbe,
    const float* __restrict__ W1, const float* __restrict__ b1,
    float* __restrict__ S, int* __restrict__ cnt)
{
  __shared__ __align__(16) float As[BK][132];
  __shared__ __align__(16) float Bs[BK][DIM];
  __shared__ int s_ij[BM], s_ik[BM];
  __shared__ __align__(16) float s_ang[BM][NBF];
  const int t = threadIdx.x;
  const int rowbase = blockIdx.x * BM;
  if (t < BM) {
    int tr = min(rowbase + t, N_TRIP-1);
    int eij = tbe[2*tr], eik = tbe[2*tr+1];
    s_ij[t] = eij; s_ik[t] = eik;
    float ax = ev[eij*3], ay = ev[eij*3+1], az = ev[eij*3+2];
    float bx = ev[eik*3], by = ev[eik*3+1], bz = ev[eik*3+2];
    float lij = fmaxf(sqrtf(ax*ax+ay*ay+az*az), 1e-6f);
    float lik = fmaxf(sqrtf(bx*bx+by*by+bz*bz), 1e-6f);
    float ct = (ax*bx+ay*by+az*bz)/(lij*lik);
    ct = fminf(fmaxf(ct, -1.f), 1.f);
    float c2 = ct*ct;
    float p0 = 1.f, p1 = ct;
    float p2 = 0.5f*(3.f*c2 - 1.f);
    float p3 = 0.5f*(5.f*c2*ct - 3.f*ct);
    float p4 = 0.125f*(35.f*c2*c2 - 30.f*c2 + 3.f);
    float rl = 1.f/lij;
    float pl = 3.14159265358979323846f * lij / CUTOFF;
    float rad0 = sinf(pl)*rl, rad1 = sinf(2.f*pl)*rl,
          rad2 = sinf(3.f*pl)*rl, rad3 = sinf(4.f*pl)*rl;
    float pp[5] = {p0,p1,p2,p3,p4};
    float rd[4] = {rad0,rad1,rad2,rad3};
#pragma unroll
    for (int a=0;a<5;a++)
#pragma unroll
      for (int r2=0;r2<4;r2++) s_ang[t][a*4+r2] = pp[a]*rd[r2];
  }
  float acc[8][8];
#pragma unroll
  for (int i=0;i<8;i++)
#pragma unroll
    for (int j=0;j<8;j++) acc[i][j]=0.f;
  const int rr = t >> 3, kk = (t & 7) << 2;
  const int ty8 = (t >> 4) << 3, tx8 = (t & 15) << 3;
  for (int kt = 0; kt < 288; kt += BK) {     // K = 276 padded to 288
    __syncthreads();
#pragma unroll
    for (int p = 0; p < 4; ++p) {
      int m = p*32 + rr;
      int c = kt + kk;
      float4 v;
      if (c < DIM)        v = *(const float4*)&ef1[(size_t)s_ij[m]*DIM + c];
      else if (c < 2*DIM) v = *(const float4*)&ef1[(size_t)s_ik[m]*DIM + (c-DIM)];
      else {
        int ca = c - 2*DIM;
        if (ca < NBF) v = *(const float4*)&s_ang[m][ca];
        else          v = make_float4(0.f,0.f,0.f,0.f);
      }
      v.x=n2nf_(v.x); v.y=n2nf_(v.y); v.z=n2nf_(v.z); v.w=n2nf_(v.w);
      As[kk+0][m]=v.x; As[kk+1][m]=v.y; As[kk+2][m]=v.z; As[kk+3][m]=v.w;
    }
    load_W(W1, kt, 2*DIM+NBF, Bs, t);
    __syncthreads();
    tile_mac(As, Bs, ty8, tx8, acc);
  }
#pragma unroll
  for (int i=0;i<8;i++) {
    int r = rowbase + ty8 + i;
    if (r < N_TRIP) {
      int e = s_ij[ty8+i];
#pragma unroll
      for (int j=0;j<8;j++) {
        float h = siluf_(acc[i][j] + b1[tx8+j]);
        atomicAdd(&S[(size_t)e*DIM + tx8 + j], h);
      }
      if ((t & 15) == 0) atomicAdd(&cnt[e], 1);
    }
  }
}

// ---- K2c: outE = ef1 + n2n(S@Wc + cnt*pb2u + upd_b) * sigmoid(ef1@tbgW + tbgb) ----
__global__ __launch_bounds__(NTHR) void k2c_edge3(
    const float* __restrict__ S, const int* __restrict__ cnt,
    const float* __restrict__ Wc, const float* __restrict__ pb2u,
    const float* __restrict__ updb,
    const float* __restrict__ tbgW, const float* __restrict__ tbgb,
    float* __restrict__ outE)
{
  __shared__ __align__(16) float As[BK][132];
  __shared__ __align__(16) float Bs[BK][DIM];
  const int t = threadIdx.x;
  const int rowbase = blockIdx.x * BM;
  const int rr = t >> 3, kk = (t & 7) << 2;
  const int ty8 = (t >> 4) << 3, tx8 = (t & 15) << 3;
  float acc1[8][8], acc2[8][8];
#pragma unroll
  for (int i=0;i<8;i++)
#pragma unroll
    for (int j=0;j<8;j++){ acc1[i][j]=0.f; acc2[i][j]=0.f; }
  for (int kt = 0; kt < DIM; kt += BK) {     // phase 1: S @ Wc
    __syncthreads();
#pragma unroll
    for (int p = 0; p < 4; ++p) {
      int m = p*32 + rr;
      int r = min(rowbase+m, N_EDGES-1);
      float4 v = *(const float4*)&S[(size_t)r*DIM + kt + kk];
      As[kk+0][m]=v.x; As[kk+1][m]=v.y; As[kk+2][m]=v.z; As[kk+3][m]=v.w;
    }
    load_W(Wc, kt, DIM, Bs, t);
    __syncthreads();
    tile_mac(As, Bs, ty8, tx8, acc1);
  }
  for (int kt = 0; kt < DIM; kt += BK) {     // phase 2: ef1 @ tbgW
    __syncthreads();
#pragma unroll
    for (int p = 0; p < 4; ++p) {
      int m = p*32 + rr;
      int r = min(rowbase+m, N_EDGES-1);
      float4 v = *(const float4*)&outE[(size_t)r*DIM + kt + kk];
      As[kk+0][m]=v.x; As[kk+1][m]=v.y; As[kk+2][m]=v.z; As[kk+3][m]=v.w;
    }
    load_W(tbgW, kt, DIM, Bs, t);
    __syncthreads();
    tile_mac(As, Bs, ty8, tx8, acc2);
  }
#pragma unroll
  for (int i=0;i<8;i++) {
    int r = rowbase + ty8 + i;
    if (r < N_EDGES) {
      float cf = (float)cnt[r];
      float e[8];
      *(float4*)&e[0] = *(const float4*)&outE[(size_t)r*DIM + tx8];
      *(float4*)&e[4] = *(const float4*)&outE[(size_t)r*DIM + tx8 + 4];
      float o[8];
#pragma unroll
      for (int j=0;j<8;j++) {
        int c = tx8 + j;
        float e3 = n2nf_(acc1[i][j] + cf*pb2u[c] + updb[c]);
        float g  = sigmoidf_(acc2[i][j] + tbgb[c]);
        o[j] = e[j] + e3 * g;
      }
      *(float4*)&outE[(size_t)r*DIM + tx8]     = *(float4*)&o[0];
      *(float4*)&outE[(size_t)r*DIM + tx8 + 4] = *(float4*)&o[4];
    }
  }
}

// ---- K3a: msg[dst] += outE row ; deg[dst] += 1 ----
__global__ __launch_bounds__(NTHR) void k3a_msg(
    const float* __restrict__ outE, const int* __restrict__ dst,
    float* __restrict__ msg, float* __restrict__ deg)
{
  int idx = blockIdx.x * NTHR + threadIdx.x;
  int e = idx >> 5;
  if (e < N_EDGES) {
    int c = (idx & 31) << 2;
    int d = dst[e];
    float4 v = *(const float4*)&outE[(size_t)e*DIM + c];
    atomicAdd(&msg[(size_t)d*DIM + c + 0], v.x);
    atomicAdd(&msg[(size_t)d*DIM + c + 1], v.y);
    atomicAdd(&msg[(size_t)d*DIM + c + 2], v.z);
    atomicAdd(&msg[(size_t)d*DIM + c + 3], v.w);
    if ((idx & 31) == 0) atomicAdd(&deg[d], 1.0f);
  }
}

// ---- K3b: H3 = silu([nf, msg/deg] @ node_W1 + b1) ----
__global__ __launch_bounds__(NTHR) void k3b_node_h(
    const float* __restrict__ nf, const float* __restrict__ msg,
    const float* __restrict__ deg,
    const float* __restrict__ W1, const float* __restrict__ b1,
    float* __restrict__ H3)
{
  __shared__ __align__(16) float As[BK][132];
  __shared__ __align__(16) float Bs[BK][DIM];
  __shared__ float s_rd[BM];
  const int t = threadIdx.x;
  const int rowbase = blockIdx.x * BM;
  if (t < BM) {
    int v = min(rowbase + t, N_NODES-1);
    s_rd[t] = 1.0f / fmaxf(deg[v], 1.0f);
  }
  float acc[8][8];
#pragma unroll
  for (int i=0;i<8;i++)
#pragma unroll
    for (int j=0;j<8;j++) acc[i][j]=0.f;
  const int rr = t >> 3, kk = (t & 7) << 2;
  const int ty8 = (t >> 4) << 3, tx8 = (t & 15) << 3;
  for (int kt = 0; kt < 2*DIM; kt += BK) {
    __syncthreads();
#pragma unroll
    for (int p = 0; p < 4; ++p) {
      int m = p*32 + rr;
      int r = min(rowbase+m, N_NODES-1);
      int c = kt + kk;
      float4 v;
      if (c < DIM) v = *(const float4*)&nf[(size_t)r*DIM + c];
      else {
        v = *(const float4*)&msg[(size_t)r*DIM + (c-DIM)];
        float s = s_rd[m];
        v.x*=s; v.y*=s; v.z*=s; v.w*=s;
      }
      As[kk+0][m]=v.x; As[kk+1][m]=v.y; As[kk+2][m]=v.z; As[kk+3][m]=v.w;
    }
    load_W(W1, kt, 2*DIM, Bs, t);
    __syncthreads();
    tile_mac(As, Bs, ty8, tx8, acc);
  }
#pragma unroll
  for (int i=0;i<8;i++) {
    int r = rowbase + ty8 + i;
    if (r < N_NODES) {
      float o[8];
#pragma unroll
      for (int j=0;j<8;j++) o[j] = siluf_(acc[i][j] + b1[tx8+j]);
      *(float4*)&H3[(size_t)r*DIM + tx8]     = *(float4*)&o[0];
      *(float4*)&H3[(size_t)r*DIM + tx8 + 4] = *(float4*)&o[4];
    }
  }
}

// ---- K3c: outN = nf + H3 @ node_W2 + b2 ----
__global__ __launch_bounds__(NTHR) void k3c_node_out(
    const float* __restrict__ nf, const float* __restrict__ H3,
    const float* __restrict__ W2, const float* __restrict__ b2,
    float* __restrict__ outN)
{
  __shared__ __align__(16) float As[BK][132];
  __shared__ __align__(16) float Bs[BK][DIM];
  const int t = threadIdx.x;
  const int rowbase = blockIdx.x * BM;
  const int rr = t >> 3, kk = (t & 7) << 2;
  const int ty8 = (t >> 4) << 3, tx8 = (t & 15) << 3;
  float acc[8][8];
#pragma unroll
  for (int i=0;i<8;i++)
#pragma unroll
    for (int j=0;j<8;j++) acc[i][j]=0.f;
  for (int kt = 0; kt < DIM; kt += BK) {
    __syncthreads();
#pragma unroll
    for (int p = 0; p < 4; ++p) {
      int m = p*32 + rr;
      int r = min(rowbase+m, N_NODES-1);
      float4 v = *(const float4*)&H3[(size_t)r*DIM + kt + kk];
      As[kk+0][m]=v.x; As[kk+1][m]=v.y; As[kk+2][m]=v.z; As[kk+3][m]=v.w;
    }
    load_W(W2, kt, DIM, Bs, t);
    __syncthreads();
    tile_mac(As, Bs, ty8, tx8, acc);
  }
#pragma unroll
  for (int i=0;i<8;i++) {
    int r = rowbase + ty8 + i;
    if (r < N_NODES) {
      float o[8];
#pragma unroll
      for (int j=0;j<8;j++)
        o[j] = nf[(size_t)r*DIM + tx8 + j] + acc[i][j] + b2[tx8+j];
      *(float4*)&outN[(size_t)r*DIM + tx8]     = *(float4*)&o[0];
      *(float4*)&outN[(size_t)r*DIM + tx8 + 4] = *(float4*)&o[4];
    }
  }
}

extern "C" void kernel_launch(void* const* d_in, const int* in_sizes, int n_in,
                              void* d_out, int out_size, void* d_ws, size_t ws_size,
                              hipStream_t stream)
{
  const float* nf  = (const float*)d_in[0];
  const float* ef  = (const float*)d_in[1];
  const float* ev  = (const float*)d_in[2];
  const int*  eidx = (const int*)d_in[3];
  // d_in[4] = three_body_indices (unused by reference)
  const int*  tbe  = (const int*)d_in[5];
  const float* eW1=(const float*)d_in[6],  *eb1=(const float*)d_in[7];
  const float* eW2=(const float*)d_in[8],  *eb2=(const float*)d_in[9];
  const float* gW =(const float*)d_in[10], *gb =(const float*)d_in[11];
  const float* pW1=(const float*)d_in[12], *pb1=(const float*)d_in[13];
  const float* pW2=(const float*)d_in[14], *pb2=(const float*)d_in[15];
  const float* uW =(const float*)d_in[16], *ub =(const float*)d_in[17];
  const float* tW =(const float*)d_in[18], *tb =(const float*)d_in[19];
  const float* nW1=(const float*)d_in[20], *nb1=(const float*)d_in[21];
  const float* nW2=(const float*)d_in[22], *nb2=(const float*)d_in[23];

  const int* src = eidx;
  const int* dst = eidx + N_EDGES;

  float* outN = (float*)d_out;
  float* outE = outN + (size_t)N_NODES*DIM;

  // workspace layout (S region is reused for msg/deg/H3 after K2c)
  char* w = (char*)d_ws;
  float* S    = (float*)w;                      // E*128 f32 (256 MB)
  int*   cnt  = (int*)(w + (size_t)N_EDGES*DIM*4);     // E ints (adjacent to S)
  float* Wc   = (float*)(w + (size_t)N_EDGES*DIM*4 + (size_t)N_EDGES*4);
  float* pb2u = Wc + DIM*DIM;
  float* msg  = S;                              // reuse: N*128
  float* deg  = msg + (size_t)N_NODES*DIM;      // N (adjacent)
  float* H3   = deg + N_NODES;                  // N*128 (adjacent)

  const int gE = (N_EDGES + BM - 1)/BM;
  const int gT = (N_TRIP  + BM - 1)/BM;
  const int gN = (N_NODES + BM - 1)/BM;

  k0_combine<<<DIM+1, DIM, 0, stream>>>(pW2, pb2, uW, Wc, pb2u);
  k1a_edge_h1<<<gE, NTHR, 0, stream>>>(nf, ef, src, dst, eW1, eb1, outE);
  k1b_edge_out<<<gE, NTHR, 0, stream>>>(ef, eW2, eb2, gW, gb, outE);
  // S (E*DIM floats) and cnt (E ints) are contiguous: one memset
  hipMemsetAsync(S, 0, (size_t)N_EDGES*DIM*4 + (size_t)N_EDGES*4, stream);
  k2b_phi<<<gT, NTHR, 0, stream>>>(outE, ev, tbe, pW1, pb1, S, cnt);
  k2c_edge3<<<gE, NTHR, 0, stream>>>(S, cnt, Wc, pb2u, ub, tW, tb, outE);
  // msg (N*DIM), deg (N) contiguous: one memset
  hipMemsetAsync(msg, 0, ((size_t)N_NODES*DIM + N_NODES)*4, stream);
  k3a_msg<<<((size_t)N_EDGES*32 + NTHR-1)/NTHR, NTHR, 0, stream>>>(outE, dst, msg, deg);
  k3b_node_h<<<gN, NTHR, 0, stream>>>(nf, msg, deg, nW1, nb1, H3);
  k3c_node_out<<<gN, NTHR, 0, stream>>>(nf, H3, nW2, nb2, outN);
}

// Round 5
// 5310.169 us; speedup vs baseline: 1.4177x; 1.4177x over previous
//
#include <hip/hip_runtime.h>
#include <math.h>

#define N_NODES 50000
#define N_EDGES 500000
#define N_TRIP  1000000
#define DIM     128
#define NBF     20
#define CUTOFF  5.0f

#define BM   128
#define BK   32
#define NTHR 256

__device__ __forceinline__ float sigmoidf_(float x){ return 1.0f/(1.0f+expf(-x)); }
__device__ __forceinline__ float siluf_(float x){ return x/(1.0f+expf(-x)); }
__device__ __forceinline__ float n2nf_(float x){ return __builtin_isfinite(x) ? x : 0.0f; }

__device__ __forceinline__ unsigned short f2bf(float x){
  union { float f; unsigned u; } c; c.f = x;
  unsigned r = c.u + 0x7fffu + ((c.u >> 16) & 1u);   // RTN-even
  return (unsigned short)(r >> 16);
}
__device__ __forceinline__ float bf2f(unsigned short h){
  union { unsigned u; float f; } c; c.u = ((unsigned)h) << 16;
  return c.f;
}

// ---- shared GEMM microkernel: 128x128 tile, 256 thr, 8x8 microtile ----
// fp32 VALU GEMM (no fp32-input MFMA on CDNA4). ~157 TF chip ceiling.
__device__ __forceinline__ void tile_mac(float As[][132], float Bs[][DIM],
                                         int ty8, int tx8, float acc[8][8]) {
#pragma unroll
  for (int k = 0; k < BK; ++k) {
    float a[8], b[8];
    *(float4*)&a[0] = *(const float4*)&As[k][ty8];
    *(float4*)&a[4] = *(const float4*)&As[k][ty8+4];
    *(float4*)&b[0] = *(const float4*)&Bs[k][tx8];
    *(float4*)&b[4] = *(const float4*)&Bs[k][tx8+4];
#pragma unroll
    for (int i = 0; i < 8; ++i)
#pragma unroll
      for (int j = 0; j < 8; ++j)
        acc[i][j] = fmaf(a[i], b[j], acc[i][j]);
  }
}

// load 32 rows of a K x 128 weight matrix into Bs (rows >= Kw zeroed)
__device__ __forceinline__ void load_W(const float* __restrict__ W, int kt, int Kw,
                                       float Bs[][DIM], int t) {
  int row = t >> 5;          // 0..7
  int col = (t & 31) << 2;   // 0..124
#pragma unroll
  for (int p = 0; p < 4; ++p) {
    int k = kt + p*8 + row;
    float4 v = make_float4(0.f,0.f,0.f,0.f);
    if (k < Kw) v = *(const float4*)&W[(size_t)k*DIM + col];
    *(float4*)&Bs[p*8+row][col] = v;
  }
}

// ---- K0: Wc = phi_W2 @ upd_W ; pb2u = phi_b2 @ upd_W ----
// Linear-algebra fold: segment_sum(m_ijk)@upd_W = segment_sum(silu(h@phiW1))@(phiW2@updW)
//                      + cnt * (phi_b2@updW). Deletes the per-triplet 128x128 GEMM.
__global__ __launch_bounds__(128) void k0_combine(
    const float* __restrict__ phiW2, const float* __restrict__ phib2,
    const float* __restrict__ updW,
    float* __restrict__ Wc, float* __restrict__ pb2u)
{
  int b = blockIdx.x, t = threadIdx.x;
  if (b < DIM) {
    float a = 0.f;
    for (int k = 0; k < DIM; ++k) a = fmaf(phiW2[b*DIM+k], updW[k*DIM+t], a);
    Wc[b*DIM+t] = a;
  } else {
    float a = 0.f;
    for (int k = 0; k < DIM; ++k) a = fmaf(phib2[k], updW[k*DIM+t], a);
    pb2u[t] = a;
  }
}

// ---- K1a: H1 = silu([nf[src], nf[dst], ef] @ edge_W1 + b1) -> outE ----
__global__ __launch_bounds__(NTHR) void k1a_edge_h1(
    const float* __restrict__ nf, const float* __restrict__ ef,
    const int* __restrict__ src, const int* __restrict__ dst,
    const float* __restrict__ W1, const float* __restrict__ b1,
    float* __restrict__ H1)
{
  __shared__ __align__(16) float As[BK][132];
  __shared__ __align__(16) float Bs[BK][DIM];
  __shared__ int s_src[BM], s_dst[BM];
  const int t = threadIdx.x;
  const int rowbase = blockIdx.x * BM;
  if (t < BM) {
    int r = min(rowbase + t, N_EDGES-1);
    s_src[t] = src[r]; s_dst[t] = dst[r];
  }
  float acc[8][8];
#pragma unroll
  for (int i=0;i<8;i++)
#pragma unroll
    for (int j=0;j<8;j++) acc[i][j]=0.f;
  const int rr = t >> 3, kk = (t & 7) << 2;
  const int ty8 = (t >> 4) << 3, tx8 = (t & 15) << 3;
  for (int kt = 0; kt < 3*DIM; kt += BK) {
    __syncthreads();
#pragma unroll
    for (int p = 0; p < 4; ++p) {
      int m = p*32 + rr;
      int c = kt + kk;
      float4 v;
      if (c < DIM)        v = *(const float4*)&nf[(size_t)s_src[m]*DIM + c];
      else if (c < 2*DIM) v = *(const float4*)&nf[(size_t)s_dst[m]*DIM + (c-DIM)];
      else { int r = min(rowbase+m, N_EDGES-1);
                          v = *(const float4*)&ef[(size_t)r*DIM + (c-2*DIM)]; }
      As[kk+0][m]=v.x; As[kk+1][m]=v.y; As[kk+2][m]=v.z; As[kk+3][m]=v.w;
    }
    load_W(W1, kt, 3*DIM, Bs, t);
    __syncthreads();
    tile_mac(As, Bs, ty8, tx8, acc);
  }
#pragma unroll
  for (int i=0;i<8;i++) {
    int r = rowbase + ty8 + i;
    if (r < N_EDGES) {
      float o[8];
#pragma unroll
      for (int j=0;j<8;j++) o[j] = siluf_(acc[i][j] + b1[tx8+j]);
      *(float4*)&H1[(size_t)r*DIM + tx8]     = *(float4*)&o[0];
      *(float4*)&H1[(size_t)r*DIM + tx8 + 4] = *(float4*)&o[4];
    }
  }
}

// ---- K1b: outE = ef + (H1@W2 + b2) * sigmoid(ef@gW + gb)  (H1 lives in outE) ----
__global__ __launch_bounds__(NTHR) void k1b_edge_out(
    const float* __restrict__ ef,
    const float* __restrict__ W2, const float* __restrict__ b2,
    const float* __restrict__ gW, const float* __restrict__ gb,
    float* __restrict__ outE)
{
  __shared__ __align__(16) float As[BK][132];
  __shared__ __align__(16) float Bs[BK][DIM];
  const int t = threadIdx.x;
  const int rowbase = blockIdx.x * BM;
  const int rr = t >> 3, kk = (t & 7) << 2;
  const int ty8 = (t >> 4) << 3, tx8 = (t & 15) << 3;
  float acc1[8][8], acc2[8][8];
#pragma unroll
  for (int i=0;i<8;i++)
#pragma unroll
    for (int j=0;j<8;j++){ acc1[i][j]=0.f; acc2[i][j]=0.f; }
  for (int kt = 0; kt < DIM; kt += BK) {     // phase 1: H1 @ W2
    __syncthreads();
#pragma unroll
    for (int p = 0; p < 4; ++p) {
      int m = p*32 + rr;
      int r = min(rowbase+m, N_EDGES-1);
      float4 v = *(const float4*)&outE[(size_t)r*DIM + kt + kk];
      As[kk+0][m]=v.x; As[kk+1][m]=v.y; As[kk+2][m]=v.z; As[kk+3][m]=v.w;
    }
    load_W(W2, kt, DIM, Bs, t);
    __syncthreads();
    tile_mac(As, Bs, ty8, tx8, acc1);
  }
  for (int kt = 0; kt < DIM; kt += BK) {     // phase 2: ef @ gW
    __syncthreads();
#pragma unroll
    for (int p = 0; p < 4; ++p) {
      int m = p*32 + rr;
      int r = min(rowbase+m, N_EDGES-1);
      float4 v = *(const float4*)&ef[(size_t)r*DIM + kt + kk];
      As[kk+0][m]=v.x; As[kk+1][m]=v.y; As[kk+2][m]=v.z; As[kk+3][m]=v.w;
    }
    load_W(gW, kt, DIM, Bs, t);
    __syncthreads();
    tile_mac(As, Bs, ty8, tx8, acc2);
  }
#pragma unroll
  for (int i=0;i<8;i++) {
    int r = rowbase + ty8 + i;
    if (r < N_EDGES) {
      float e[8];
      *(float4*)&e[0] = *(const float4*)&ef[(size_t)r*DIM + tx8];
      *(float4*)&e[4] = *(const float4*)&ef[(size_t)r*DIM + tx8 + 4];
      float o[8];
#pragma unroll
      for (int j=0;j<8;j++) {
        float ep = acc1[i][j] + b2[tx8+j];
        float g  = sigmoidf_(acc2[i][j] + gb[tx8+j]);
        o[j] = e[j] + ep * g;
      }
      *(float4*)&outE[(size_t)r*DIM + tx8]     = *(float4*)&o[0];
      *(float4*)&outE[(size_t)r*DIM + tx8 + 4] = *(float4*)&o[4];
    }
  }
}

// ---- K2b: per-triplet phi layer-1, coalesced atomic segment-sum into S ----
// Epilogue stages each wave's rows in LDS, then issues atomics where each
// instruction's 64 lanes cover 64 CONSECUTIVE dwords of one S row (packed
// sectors). Old tx8-strided atomics caused 8x HBM write amplification
// (4 B atomic -> 32 B sector): measured WRITE_SIZE 4.03 GB vs 0.5 GB payload.
__global__ __launch_bounds__(NTHR) void k2b_phi(
    const float* __restrict__ ef1, const float* __restrict__ ev,
    const int* __restrict__ tbe,
    const float* __restrict__ W1, const float* __restrict__ b1,
    float* __restrict__ S, int* __restrict__ cnt)
{
  // As (32x132) | Bs (32x128) in one buffer; epilogue reuses it as 4 per-wave
  // 16x129 f32 staging tiles (4*2064 = 8256 <= 8320 floats).
  __shared__ __align__(16) float smem[BK*132 + BK*DIM];
  float (*As)[132] = (float(*)[132])smem;
  float (*Bs)[DIM] = (float(*)[DIM])(smem + BK*132);
  __shared__ int s_ij[BM], s_ik[BM];
  __shared__ unsigned short s_angh[BM][NBF];   // bf16 angle feats (LDS diet: 44.5->39.4 KB, 4 blk/CU)
  const int t = threadIdx.x;
  const int rowbase = blockIdx.x * BM;
  if (t < BM) {
    int tr = min(rowbase + t, N_TRIP-1);
    int eij = tbe[2*tr], eik = tbe[2*tr+1];
    s_ij[t] = eij; s_ik[t] = eik;
    float ax = ev[eij*3], ay = ev[eij*3+1], az = ev[eij*3+2];
    float bx = ev[eik*3], by = ev[eik*3+1], bz = ev[eik*3+2];
    float lij = fmaxf(sqrtf(ax*ax+ay*ay+az*az), 1e-6f);
    float lik = fmaxf(sqrtf(bx*bx+by*by+bz*bz), 1e-6f);
    float ct = (ax*bx+ay*by+az*bz)/(lij*lik);
    ct = fminf(fmaxf(ct, -1.f), 1.f);
    float c2 = ct*ct;
    float p0 = 1.f, p1 = ct;
    float p2 = 0.5f*(3.f*c2 - 1.f);
    float p3 = 0.5f*(5.f*c2*ct - 3.f*ct);
    float p4 = 0.125f*(35.f*c2*c2 - 30.f*c2 + 3.f);
    float rl = 1.f/lij;
    float pl = 3.14159265358979323846f * lij / CUTOFF;
    float rad0 = sinf(pl)*rl, rad1 = sinf(2.f*pl)*rl,
          rad2 = sinf(3.f*pl)*rl, rad3 = sinf(4.f*pl)*rl;
    float pp[5] = {p0,p1,p2,p3,p4};
    float rd[4] = {rad0,rad1,rad2,rad3};
#pragma unroll
    for (int a=0;a<5;a++)
#pragma unroll
      for (int r2=0;r2<4;r2++) s_angh[t][a*4+r2] = f2bf(pp[a]*rd[r2]);
  }
  float acc[8][8];
#pragma unroll
  for (int i=0;i<8;i++)
#pragma unroll
    for (int j=0;j<8;j++) acc[i][j]=0.f;
  const int rr = t >> 3, kk = (t & 7) << 2;
  const int ty8 = (t >> 4) << 3, tx8 = (t & 15) << 3;
  for (int kt = 0; kt < 288; kt += BK) {     // K = 276 padded to 288
    __syncthreads();
#pragma unroll
    for (int p = 0; p < 4; ++p) {
      int m = p*32 + rr;
      int c = kt + kk;
      float4 v;
      if (c < DIM)        v = *(const float4*)&ef1[(size_t)s_ij[m]*DIM + c];
      else if (c < 2*DIM) v = *(const float4*)&ef1[(size_t)s_ik[m]*DIM + (c-DIM)];
      else {
        int ca = c - 2*DIM;
        if (ca < NBF) v = make_float4(bf2f(s_angh[m][ca]),   bf2f(s_angh[m][ca+1]),
                                      bf2f(s_angh[m][ca+2]), bf2f(s_angh[m][ca+3]));
        else          v = make_float4(0.f,0.f,0.f,0.f);
      }
      v.x=n2nf_(v.x); v.y=n2nf_(v.y); v.z=n2nf_(v.z); v.w=n2nf_(v.w);
      As[kk+0][m]=v.x; As[kk+1][m]=v.y; As[kk+2][m]=v.z; As[kk+3][m]=v.w;
    }
    load_W(W1, kt, 2*DIM+NBF, Bs, t);
    __syncthreads();
    tile_mac(As, Bs, ty8, tx8, acc);
  }
  // ---- coalesced atomic epilogue ----
  const int wave = t >> 6;
  const int lane = t & 63;
  const int row_local = ty8 - wave*32;       // 0,8,16,24 within wave's 32-row block
  float* sT = smem + wave * (16*129);        // per-wave staging: 16 rows x 129
  __syncthreads();                           // K-loop LDS reads complete before reuse
  for (int pass = 0; pass < 2; ++pass) {
    if ((row_local >> 4) == pass) {
      int rbase = row_local & 15;            // 0 or 8
#pragma unroll
      for (int i = 0; i < 8; ++i)
#pragma unroll
        for (int j = 0; j < 8; ++j)
          sT[(rbase + i)*129 + tx8 + j] = siluf_(acc[i][j] + b1[tx8+j]);
    }
    __syncthreads();
#pragma unroll 4
    for (int r = 0; r < 16; ++r) {
      int rt = wave*32 + pass*16 + r;        // tile row
      if (rowbase + rt < N_TRIP) {
        int e = s_ij[rt];
        float v0 = sT[r*129 + lane];
        float v1 = sT[r*129 + 64 + lane];
        atomicAdd(&S[(size_t)e*DIM + lane], v0);        // 64 consecutive dwords/instr
        atomicAdd(&S[(size_t)e*DIM + 64 + lane], v1);
      }
    }
    __syncthreads();
  }
  if (t < BM && rowbase + t < N_TRIP) atomicAdd(&cnt[s_ij[t]], 1);
}

// ---- K2c: outE = ef1 + n2n(S@Wc + cnt*pb2u + upd_b) * sigmoid(ef1@tbgW + tbgb) ----
__global__ __launch_bounds__(NTHR) void k2c_edge3(
    const float* __restrict__ S, const int* __restrict__ cnt,
    const float* __restrict__ Wc, const float* __restrict__ pb2u,
    const float* __restrict__ updb,
    const float* __restrict__ tbgW, const float* __restrict__ tbgb,
    float* __restrict__ outE)
{
  __shared__ __align__(16) float As[BK][132];
  __shared__ __align__(16) float Bs[BK][DIM];
  const int t = threadIdx.x;
  const int rowbase = blockIdx.x * BM;
  const int rr = t >> 3, kk = (t & 7) << 2;
  const int ty8 = (t >> 4) << 3, tx8 = (t & 15) << 3;
  float acc1[8][8], acc2[8][8];
#pragma unroll
  for (int i=0;i<8;i++)
#pragma unroll
    for (int j=0;j<8;j++){ acc1[i][j]=0.f; acc2[i][j]=0.f; }
  for (int kt = 0; kt < DIM; kt += BK) {     // phase 1: S @ Wc
    __syncthreads();
#pragma unroll
    for (int p = 0; p < 4; ++p) {
      int m = p*32 + rr;
      int r = min(rowbase+m, N_EDGES-1);
      float4 v = *(const float4*)&S[(size_t)r*DIM + kt + kk];
      As[kk+0][m]=v.x; As[kk+1][m]=v.y; As[kk+2][m]=v.z; As[kk+3][m]=v.w;
    }
    load_W(Wc, kt, DIM, Bs, t);
    __syncthreads();
    tile_mac(As, Bs, ty8, tx8, acc1);
  }
  for (int kt = 0; kt < DIM; kt += BK) {     // phase 2: ef1 @ tbgW
    __syncthreads();
#pragma unroll
    for (int p = 0; p < 4; ++p) {
      int m = p*32 + rr;
      int r = min(rowbase+m, N_EDGES-1);
      float4 v = *(const float4*)&outE[(size_t)r*DIM + kt + kk];
      As[kk+0][m]=v.x; As[kk+1][m]=v.y; As[kk+2][m]=v.z; As[kk+3][m]=v.w;
    }
    load_W(tbgW, kt, DIM, Bs, t);
    __syncthreads();
    tile_mac(As, Bs, ty8, tx8, acc2);
  }
#pragma unroll
  for (int i=0;i<8;i++) {
    int r = rowbase + ty8 + i;
    if (r < N_EDGES) {
      float cf = (float)cnt[r];
      float e[8];
      *(float4*)&e[0] = *(const float4*)&outE[(size_t)r*DIM + tx8];
      *(float4*)&e[4] = *(const float4*)&outE[(size_t)r*DIM + tx8 + 4];
      float o[8];
#pragma unroll
      for (int j=0;j<8;j++) {
        int c = tx8 + j;
        float e3 = n2nf_(acc1[i][j] + cf*pb2u[c] + updb[c]);
        float g  = sigmoidf_(acc2[i][j] + tbgb[c]);
        o[j] = e[j] + e3 * g;
      }
      *(float4*)&outE[(size_t)r*DIM + tx8]     = *(float4*)&o[0];
      *(float4*)&outE[(size_t)r*DIM + tx8 + 4] = *(float4*)&o[4];
    }
  }
}

// ---- K3a: msg[dst] += outE row ; deg[dst] += 1 ----
// (atomic addresses already lane-contiguous per row: 32 lanes x float4 = 512 B)
__global__ __launch_bounds__(NTHR) void k3a_msg(
    const float* __restrict__ outE, const int* __restrict__ dst,
    float* __restrict__ msg, float* __restrict__ deg)
{
  int idx = blockIdx.x * NTHR + threadIdx.x;
  int e = idx >> 5;
  if (e < N_EDGES) {
    int c = (idx & 31) << 2;
    int d = dst[e];
    float4 v = *(const float4*)&outE[(size_t)e*DIM + c];
    atomicAdd(&msg[(size_t)d*DIM + c + 0], v.x);
    atomicAdd(&msg[(size_t)d*DIM + c + 1], v.y);
    atomicAdd(&msg[(size_t)d*DIM + c + 2], v.z);
    atomicAdd(&msg[(size_t)d*DIM + c + 3], v.w);
    if ((idx & 31) == 0) atomicAdd(&deg[d], 1.0f);
  }
}

// ---- K3b: H3 = silu([nf, msg/deg] @ node_W1 + b1) ----
__global__ __launch_bounds__(NTHR) void k3b_node_h(
    const float* __restrict__ nf, const float* __restrict__ msg,
    const float* __restrict__ deg,
    const float* __restrict__ W1, const float* __restrict__ b1,
    float* __restrict__ H3)
{
  __shared__ __align__(16) float As[BK][132];
  __shared__ __align__(16) float Bs[BK][DIM];
  __shared__ float s_rd[BM];
  const int t = threadIdx.x;
  const int rowbase = blockIdx.x * BM;
  if (t < BM) {
    int v = min(rowbase + t, N_NODES-1);
    s_rd[t] = 1.0f / fmaxf(deg[v], 1.0f);
  }
  float acc[8][8];
#pragma unroll
  for (int i=0;i<8;i++)
#pragma unroll
    for (int j=0;j<8;j++) acc[i][j]=0.f;
  const int rr = t >> 3, kk = (t & 7) << 2;
  const int ty8 = (t >> 4) << 3, tx8 = (t & 15) << 3;
  for (int kt = 0; kt < 2*DIM; kt += BK) {
    __syncthreads();
#pragma unroll
    for (int p = 0; p < 4; ++p) {
      int m = p*32 + rr;
      int r = min(rowbase+m, N_NODES-1);
      int c = kt + kk;
      float4 v;
      if (c < DIM) v = *(const float4*)&nf[(size_t)r*DIM + c];
      else {
        v = *(const float4*)&msg[(size_t)r*DIM + (c-DIM)];
        float s = s_rd[m];
        v.x*=s; v.y*=s; v.z*=s; v.w*=s;
      }
      As[kk+0][m]=v.x; As[kk+1][m]=v.y; As[kk+2][m]=v.z; As[kk+3][m]=v.w;
    }
    load_W(W1, kt, 2*DIM, Bs, t);
    __syncthreads();
    tile_mac(As, Bs, ty8, tx8, acc);
  }
#pragma unroll
  for (int i=0;i<8;i++) {
    int r = rowbase + ty8 + i;
    if (r < N_NODES) {
      float o[8];
#pragma unroll
      for (int j=0;j<8;j++) o[j] = siluf_(acc[i][j] + b1[tx8+j]);
      *(float4*)&H3[(size_t)r*DIM + tx8]     = *(float4*)&o[0];
      *(float4*)&H3[(size_t)r*DIM + tx8 + 4] = *(float4*)&o[4];
    }
  }
}

// ---- K3c: outN = nf + H3 @ node_W2 + b2 ----
__global__ __launch_bounds__(NTHR) void k3c_node_out(
    const float* __restrict__ nf, const float* __restrict__ H3,
    const float* __restrict__ W2, const float* __restrict__ b2,
    float* __restrict__ outN)
{
  __shared__ __align__(16) float As[BK][132];
  __shared__ __align__(16) float Bs[BK][DIM];
  const int t = threadIdx.x;
  const int rowbase = blockIdx.x * BM;
  const int rr = t >> 3, kk = (t & 7) << 2;
  const int ty8 = (t >> 4) << 3, tx8 = (t & 15) << 3;
  float acc[8][8];
#pragma unroll
  for (int i=0;i<8;i++)
#pragma unroll
    for (int j=0;j<8;j++) acc[i][j]=0.f;
  for (int kt = 0; kt < DIM; kt += BK) {
    __syncthreads();
#pragma unroll
    for (int p = 0; p < 4; ++p) {
      int m = p*32 + rr;
      int r = min(rowbase+m, N_NODES-1);
      float4 v = *(const float4*)&H3[(size_t)r*DIM + kt + kk];
      As[kk+0][m]=v.x; As[kk+1][m]=v.y; As[kk+2][m]=v.z; As[kk+3][m]=v.w;
    }
    load_W(W2, kt, DIM, Bs, t);
    __syncthreads();
    tile_mac(As, Bs, ty8, tx8, acc);
  }
#pragma unroll
  for (int i=0;i<8;i++) {
    int r = rowbase + ty8 + i;
    if (r < N_NODES) {
      float o[8];
#pragma unroll
      for (int j=0;j<8;j++)
        o[j] = nf[(size_t)r*DIM + tx8 + j] + acc[i][j] + b2[tx8+j];
      *(float4*)&outN[(size_t)r*DIM + tx8]     = *(float4*)&o[0];
      *(float4*)&outN[(size_t)r*DIM + tx8 + 4] = *(float4*)&o[4];
    }
  }
}

extern "C" void kernel_launch(void* const* d_in, const int* in_sizes, int n_in,
                              void* d_out, int out_size, void* d_ws, size_t ws_size,
                              hipStream_t stream)
{
  const float* nf  = (const float*)d_in[0];
  const float* ef  = (const float*)d_in[1];
  const float* ev  = (const float*)d_in[2];
  const int*  eidx = (const int*)d_in[3];
  // d_in[4] = three_body_indices (unused by reference)
  const int*  tbe  = (const int*)d_in[5];
  const float* eW1=(const float*)d_in[6],  *eb1=(const float*)d_in[7];
  const float* eW2=(const float*)d_in[8],  *eb2=(const float*)d_in[9];
  const float* gW =(const float*)d_in[10], *gb =(const float*)d_in[11];
  const float* pW1=(const float*)d_in[12], *pb1=(const float*)d_in[13];
  const float* pW2=(const float*)d_in[14], *pb2=(const float*)d_in[15];
  const float* uW =(const float*)d_in[16], *ub =(const float*)d_in[17];
  const float* tW =(const float*)d_in[18], *tb =(const float*)d_in[19];
  const float* nW1=(const float*)d_in[20], *nb1=(const float*)d_in[21];
  const float* nW2=(const float*)d_in[22], *nb2=(const float*)d_in[23];

  const int* src = eidx;
  const int* dst = eidx + N_EDGES;

  float* outN = (float*)d_out;
  float* outE = outN + (size_t)N_NODES*DIM;

  // workspace layout (S region is reused for msg/deg/H3 after K2c)
  char* w = (char*)d_ws;
  float* S    = (float*)w;                      // E*128 f32 (256 MB)
  int*   cnt  = (int*)(w + (size_t)N_EDGES*DIM*4);     // E ints (adjacent to S)
  float* Wc   = (float*)(w + (size_t)N_EDGES*DIM*4 + (size_t)N_EDGES*4);
  float* pb2u = Wc + DIM*DIM;
  float* msg  = S;                              // reuse: N*128
  float* deg  = msg + (size_t)N_NODES*DIM;      // N (adjacent)
  float* H3   = deg + N_NODES;                  // N*128 (adjacent)

  const int gE = (N_EDGES + BM - 1)/BM;
  const int gT = (N_TRIP  + BM - 1)/BM;
  const int gN = (N_NODES + BM - 1)/BM;

  k0_combine<<<DIM+1, DIM, 0, stream>>>(pW2, pb2, uW, Wc, pb2u);
  k1a_edge_h1<<<gE, NTHR, 0, stream>>>(nf, ef, src, dst, eW1, eb1, outE);
  k1b_edge_out<<<gE, NTHR, 0, stream>>>(ef, eW2, eb2, gW, gb, outE);
  // S (E*DIM floats) and cnt (E ints) are contiguous: one memset
  hipMemsetAsync(S, 0, (size_t)N_EDGES*DIM*4 + (size_t)N_EDGES*4, stream);
  k2b_phi<<<gT, NTHR, 0, stream>>>(outE, ev, tbe, pW1, pb1, S, cnt);
  k2c_edge3<<<gE, NTHR, 0, stream>>>(S, cnt, Wc, pb2u, ub, tW, tb, outE);
  // msg (N*DIM), deg (N) contiguous: one memset
  hipMemsetAsync(msg, 0, ((size_t)N_NODES*DIM + N_NODES)*4, stream);
  k3a_msg<<<((size_t)N_EDGES*32 + NTHR-1)/NTHR, NTHR, 0, stream>>>(outE, dst, msg, deg);
  k3b_node_h<<<gN, NTHR, 0, stream>>>(nf, msg, deg, nW1, nb1, H3);
  k3c_node_out<<<gN, NTHR, 0, stream>>>(nf, H3, nW2, nb2, outN);
}

// Round 8
// 3408.847 us; speedup vs baseline: 2.2085x; 1.5578x over previous
//
#include <hip/hip_runtime.h>
#include <math.h>

#define N_NODES 50000
#define N_EDGES 500000
#define N_TRIP  1000000
#define DIM     128
#define NBF     20
#define CUTOFF  5.0f

#define BM   128
#define BK   32
#define NTHR 256
#define ASTR 72   // LDS row stride in bf16 units: 64 K + 8 pad -> 144 B (hits bank floor)

typedef __attribute__((ext_vector_type(8))) short bf8;     // 8 bf16 (4 VGPRs) - MFMA A/B frag
typedef __attribute__((ext_vector_type(4))) float f32x4;   // MFMA C/D frag
typedef unsigned short ushort_t;

__device__ __forceinline__ float sigmoidf_(float x){ return 1.0f/(1.0f+expf(-x)); }
__device__ __forceinline__ float siluf_(float x){ return x/(1.0f+expf(-x)); }
__device__ __forceinline__ float n2nf_(float x){ return __builtin_isfinite(x) ? x : 0.0f; }

// HW packed f32->bf16 (RNE), 1 inst / 2 elems. lo16 = cvt(a), hi16 = cvt(b).
__device__ __forceinline__ unsigned cvtpk(float a, float b){
  unsigned r; asm("v_cvt_pk_bf16_f32 %0, %1, %2" : "=v"(r) : "v"(a), "v"(b)); return r;
}

// ---------------- fp32 VALU GEMM helpers (kept for node-scale kernels) ----------------
__device__ __forceinline__ void tile_mac(float As[][132], float Bs[][DIM],
                                         int ty8, int tx8, float acc[8][8]) {
#pragma unroll
  for (int k = 0; k < BK; ++k) {
    float a[8], b[8];
    *(float4*)&a[0] = *(const float4*)&As[k][ty8];
    *(float4*)&a[4] = *(const float4*)&As[k][ty8+4];
    *(float4*)&b[0] = *(const float4*)&Bs[k][tx8];
    *(float4*)&b[4] = *(const float4*)&Bs[k][tx8+4];
#pragma unroll
    for (int i = 0; i < 8; ++i)
#pragma unroll
      for (int j = 0; j < 8; ++j)
        acc[i][j] = fmaf(a[i], b[j], acc[i][j]);
  }
}

__device__ __forceinline__ void load_W(const float* __restrict__ W, int kt, int Kw,
                                       float Bs[][DIM], int t) {
  int row = t >> 5;
  int col = (t & 31) << 2;
#pragma unroll
  for (int p = 0; p < 4; ++p) {
    int k = kt + p*8 + row;
    float4 v = make_float4(0.f,0.f,0.f,0.f);
    if (k < Kw) v = *(const float4*)&W[(size_t)k*DIM + col];
    *(float4*)&Bs[p*8+row][col] = v;
  }
}

// ---------------- MFMA building blocks ----------------
// One K=64 slice: 4 A-frag + 16 B-frag ds_read_b128, 32 MFMA per wave.
// Wave w owns output rows 32w..32w+31 (tr in {0,1}), all 128 cols (tc 0..7).
__device__ __forceinline__ void mfma_step(const ushort_t* A_lds, const ushort_t* B_lds,
                                          int wave, int lane, f32x4 (&acc)[2][8])
{
  const int l15 = lane & 15, lhi = lane >> 4;
#pragma unroll
  for (int k0 = 0; k0 < 64; k0 += 32) {
    bf8 a0 = *(const bf8*)(A_lds + (wave*32 +      l15)*ASTR + k0 + 8*lhi);
    bf8 a1 = *(const bf8*)(A_lds + (wave*32 + 16 + l15)*ASTR + k0 + 8*lhi);
#pragma unroll
    for (int tc = 0; tc < 8; ++tc) {
      bf8 b = *(const bf8*)(B_lds + (tc*16 + l15)*ASTR + k0 + 8*lhi);
      acc[0][tc] = __builtin_amdgcn_mfma_f32_16x16x32_bf16(a0, b, acc[0][tc], 0, 0, 0);
      acc[1][tc] = __builtin_amdgcn_mfma_f32_16x16x32_bf16(a1, b, acc[1][tc], 0, 0, 0);
    }
  }
}

// read 32 contiguous fp32 (optionally nan_to_num) into 8 float4 regs
template<bool N2N>
__device__ __forceinline__ void load32(const float* s, float4* x){
#pragma unroll
  for (int q=0;q<8;q++) x[q] = ((const float4*)s)[q];
  if (N2N) {
#pragma unroll
    for (int q=0;q<8;q++){ x[q].x=n2nf_(x[q].x); x[q].y=n2nf_(x[q].y);
                           x[q].z=n2nf_(x[q].z); x[q].w=n2nf_(x[q].w); }
  }
}

// convert 32 fp32 -> 32 bf16 and store 64 B to LDS (16B-aligned dest)
__device__ __forceinline__ void cvt_store32(const float4* x, ushort_t* d){
#pragma unroll
  for (int q=0;q<4;q++) {
    float4 a = x[q*2], b = x[q*2+1];
    uint4 o;
    o.x = cvtpk(a.x,a.y); o.y = cvtpk(a.z,a.w);
    o.z = cvtpk(b.x,b.y); o.w = cvtpk(b.z,b.w);
    ((uint4*)d)[q] = o;
  }
}

// stage 128 cols x 64 k of a pre-transposed bf16 weight [col][Kpad] into B_lds
__device__ __forceinline__ void stage_B(const ushort_t* Wt, int Kpad, int k0g,
                                        ushort_t* B_lds, int t){
  int col = t >> 1, sh = t & 1;
  const float4* s = (const float4*)(Wt + (size_t)col*Kpad + k0g + sh*32);
  float4 v0=s[0], v1=s[1], v2=s[2], v3=s[3];
  float4* d = (float4*)(B_lds + col*ASTR + sh*32);
  d[0]=v0; d[1]=v1; d[2]=v2; d[3]=v3;
}

// ---- P: transpose + bf16-convert a (K x 128) fp32 weight to [128][Kpad] ----
__global__ __launch_bounds__(256) void w2bf_t(const float* __restrict__ W,
                                              ushort_t* __restrict__ out,
                                              int K, int Kpad)
{
  int idx = blockIdx.x*256 + threadIdx.x;
  if (idx < 128*Kpad) {
    int c = idx / Kpad, k = idx - c*Kpad;
    float v = (k < K) ? W[(size_t)k*DIM + c] : 0.f;
    out[idx] = (ushort_t)cvtpk(v, 0.f);
  }
}

// ---- K0: Wc = phi_W2 @ upd_W ; pb2u = phi_b2 @ upd_W (fp32, tiny) ----
// Fold: segment_sum(m_ijk)@upd_W = segment_sum(silu(h@phiW1))@(phiW2@updW) + cnt*(phi_b2@updW)
__global__ __launch_bounds__(128) void k0_combine(
    const float* __restrict__ phiW2, const float* __restrict__ phib2,
    const float* __restrict__ updW,
    float* __restrict__ Wc, float* __restrict__ pb2u)
{
  int b = blockIdx.x, t = threadIdx.x;
  if (b < DIM) {
    float a = 0.f;
    for (int k = 0; k < DIM; ++k) a = fmaf(phiW2[b*DIM+k], updW[k*DIM+t], a);
    Wc[b*DIM+t] = a;
  } else {
    float a = 0.f;
    for (int k = 0; k < DIM; ++k) a = fmaf(phib2[k], updW[k*DIM+t], a);
    pb2u[t] = a;
  }
}

// ---- K1a (MFMA): H1 = silu([nf[src], nf[dst], ef] @ edge_W1 + b1) ----
__global__ __launch_bounds__(NTHR) void k1a_mfma(
    const float* __restrict__ nf, const float* __restrict__ ef,
    const int* __restrict__ src, const int* __restrict__ dst,
    const ushort_t* __restrict__ Wt, const float* __restrict__ b1,
    float* __restrict__ H1)
{
  __shared__ __align__(16) ushort_t A_lds[128*ASTR];
  __shared__ __align__(16) ushort_t B_lds[128*ASTR];
  __shared__ int s_src[128], s_dst[128];
  const int t = threadIdx.x, rowbase = blockIdx.x * BM;
  if (t < 128) { int r = min(rowbase+t, N_EDGES-1); s_src[t]=src[r]; s_dst[t]=dst[r]; }
  const int wave = t>>6, lane = t&63, srow = t>>1, sh = t&1;
  f32x4 acc[2][8];
#pragma unroll
  for (int i=0;i<2;i++)
#pragma unroll
    for (int j=0;j<8;j++) acc[i][j] = (f32x4){0.f,0.f,0.f,0.f};
  __syncthreads();
  for (int step = 0; step < 6; ++step) {
    const float* base;
    if (step < 2)      base = nf + (size_t)s_src[srow]*DIM;
    else if (step < 4) base = nf + (size_t)s_dst[srow]*DIM;
    else               base = ef + (size_t)min(rowbase+srow, N_EDGES-1)*DIM;
    float4 x[8];
    load32<false>(base + (step&1)*64 + sh*32, x);
    cvt_store32(x, A_lds + srow*ASTR + sh*32);
    stage_B(Wt, 384, step*64, B_lds, t);
    __syncthreads();
    mfma_step(A_lds, B_lds, wave, lane, acc);
    __syncthreads();
  }
  const int l15 = lane&15, lhi = lane>>4;
#pragma unroll
  for (int tc=0;tc<8;tc++){
    int c = tc*16 + l15;
    float bb = b1[c];
#pragma unroll
    for (int tr=0;tr<2;tr++)
#pragma unroll
      for (int reg=0;reg<4;reg++){
        int r = rowbase + wave*32 + tr*16 + lhi*4 + reg;
        if (r < N_EDGES) H1[(size_t)r*DIM + c] = siluf_(acc[tr][tc][reg] + bb);
      }
  }
}

// ---- K1b (MFMA): outE = ef + (H1@W2 + b2) * sigmoid(ef@gW + gb); H1 lives in outE ----
__global__ __launch_bounds__(NTHR) void k1b_mfma(
    const float* __restrict__ ef,
    const ushort_t* __restrict__ Wt2, const float* __restrict__ b2,
    const ushort_t* __restrict__ Wtg, const float* __restrict__ gb,
    float* outE)
{
  __shared__ __align__(16) ushort_t A_lds[128*ASTR];
  __shared__ __align__(16) ushort_t B_lds[128*ASTR];
  const int t = threadIdx.x, rowbase = blockIdx.x * BM;
  const int wave = t>>6, lane = t&63, srow = t>>1, sh = t&1;
  const int rr = min(rowbase+srow, N_EDGES-1);
  f32x4 acc1[2][8], acc2[2][8];
#pragma unroll
  for (int i=0;i<2;i++)
#pragma unroll
    for (int j=0;j<8;j++){ acc1[i][j]=(f32x4){0.f,0.f,0.f,0.f}; acc2[i][j]=(f32x4){0.f,0.f,0.f,0.f}; }
  for (int step = 0; step < 2; ++step) {       // phase 1: H1 @ W2
    float4 x[8];
    load32<false>(outE + (size_t)rr*DIM + step*64 + sh*32, x);
    cvt_store32(x, A_lds + srow*ASTR + sh*32);
    stage_B(Wt2, 128, step*64, B_lds, t);
    __syncthreads();
    mfma_step(A_lds, B_lds, wave, lane, acc1);
    __syncthreads();
  }
  for (int step = 0; step < 2; ++step) {       // phase 2: ef @ gW
    float4 x[8];
    load32<false>(ef + (size_t)rr*DIM + step*64 + sh*32, x);
    cvt_store32(x, A_lds + srow*ASTR + sh*32);
    stage_B(Wtg, 128, step*64, B_lds, t);
    __syncthreads();
    mfma_step(A_lds, B_lds, wave, lane, acc2);
    __syncthreads();
  }
  const int l15 = lane&15, lhi = lane>>4;
#pragma unroll
  for (int tc=0;tc<8;tc++){
    int c = tc*16 + l15;
    float bb2 = b2[c], bbg = gb[c];
#pragma unroll
    for (int tr=0;tr<2;tr++)
#pragma unroll
      for (int reg=0;reg<4;reg++){
        int r = rowbase + wave*32 + tr*16 + lhi*4 + reg;
        if (r < N_EDGES) {
          size_t o = (size_t)r*DIM + c;
          float e  = ef[o];
          outE[o] = e + (acc1[tr][tc][reg] + bb2) * sigmoidf_(acc2[tr][tc][reg] + bbg);
        }
      }
  }
}

// ---- K2b (MFMA): per-triplet phi layer-1, packed-sector atomic segment-sum into S ----
__global__ __launch_bounds__(NTHR) void k2b_mfma(
    const float* __restrict__ ef1, const float* __restrict__ ev,
    const int* __restrict__ tbe,
    const ushort_t* __restrict__ Wt, const float* __restrict__ b1,
    float* __restrict__ S, int* __restrict__ cnt)
{
  __shared__ __align__(16) ushort_t A_lds[128*ASTR];
  __shared__ __align__(16) ushort_t B_lds[128*ASTR];
  __shared__ int s_ij[128], s_ik[128];
  __shared__ __align__(16) ushort_t s_ang[128*32];   // bf16, cols 20..31 zero
  const int t = threadIdx.x, rowbase = blockIdx.x * BM;
  if (t < 128) {
    int tr_ = min(rowbase + t, N_TRIP-1);
    int eij = tbe[2*tr_], eik = tbe[2*tr_+1];
    s_ij[t] = eij; s_ik[t] = eik;
    float ax = ev[eij*3], ay = ev[eij*3+1], az = ev[eij*3+2];
    float bx = ev[eik*3], by = ev[eik*3+1], bz = ev[eik*3+2];
    float lij = fmaxf(sqrtf(ax*ax+ay*ay+az*az), 1e-6f);
    float lik = fmaxf(sqrtf(bx*bx+by*by+bz*bz), 1e-6f);
    float ct = (ax*bx+ay*by+az*bz)/(lij*lik);
    ct = fminf(fmaxf(ct, -1.f), 1.f);
    float c2 = ct*ct;
    float pp[5];
    pp[0]=1.f; pp[1]=ct;
    pp[2]=0.5f*(3.f*c2 - 1.f);
    pp[3]=0.5f*(5.f*c2*ct - 3.f*ct);
    pp[4]=0.125f*(35.f*c2*c2 - 30.f*c2 + 3.f);
    float rl = 1.f/lij;
    float pl = 3.14159265358979323846f * lij / CUTOFF;
    float rd[4] = { sinf(pl)*rl, sinf(2.f*pl)*rl, sinf(3.f*pl)*rl, sinf(4.f*pl)*rl };
#pragma unroll
    for (int a=0;a<5;a++)
#pragma unroll
      for (int r2=0;r2<4;r2++) s_ang[t*32 + a*4+r2] = (ushort_t)cvtpk(pp[a]*rd[r2], 0.f);
#pragma unroll
    for (int z=20; z<32; ++z) s_ang[t*32 + z] = 0;
  }
  const int wave = t>>6, lane = t&63, srow = t>>1, sh = t&1;
  f32x4 acc[2][8];
#pragma unroll
  for (int i=0;i<2;i++)
#pragma unroll
    for (int j=0;j<8;j++) acc[i][j] = (f32x4){0.f,0.f,0.f,0.f};
  __syncthreads();
  for (int step = 0; step < 5; ++step) {       // K = 320 (276 zero-padded)
    if (step < 4) {
      int e = (step < 2) ? s_ij[srow] : s_ik[srow];
      float4 x[8];
      load32<true>(ef1 + (size_t)e*DIM + (step&1)*64 + sh*32, x);
      cvt_store32(x, A_lds + srow*ASTR + sh*32);
    } else {
      uint4* d = (uint4*)(A_lds + srow*ASTR + sh*32);
      if (sh == 0) {
        const uint4* sa = (const uint4*)(s_ang + srow*32);
        d[0]=sa[0]; d[1]=sa[1]; d[2]=sa[2]; d[3]=sa[3];
      } else {
        uint4 z = {0u,0u,0u,0u};
        d[0]=z; d[1]=z; d[2]=z; d[3]=z;
      }
    }
    stage_B(Wt, 320, step*64, B_lds, t);
    __syncthreads();
    mfma_step(A_lds, B_lds, wave, lane, acc);
    __syncthreads();
  }
  // epilogue: each atomic instr covers 4 rows x 16 contiguous cols (64B runs -> packed sectors)
  const int l15 = lane&15, lhi = lane>>4;
#pragma unroll
  for (int tc=0;tc<8;tc++){
    int c = tc*16 + l15;
    float bb = b1[c];
#pragma unroll
    for (int tr=0;tr<2;tr++)
#pragma unroll
      for (int reg=0;reg<4;reg++){
        int local = wave*32 + tr*16 + lhi*4 + reg;
        if (rowbase + local < N_TRIP) {
          int e = s_ij[local];
          atomicAdd(&S[(size_t)e*DIM + c], siluf_(acc[tr][tc][reg] + bb));
        }
      }
  }
  {
    int local = wave*32 + lane;
    if (lane < 32 && rowbase + local < N_TRIP) atomicAdd(&cnt[s_ij[local]], 1);
  }
}

// ---- K2c (MFMA): outE = ef1 + n2n(S@Wc + cnt*pb2u + upd_b) * sigmoid(ef1@tbgW + tbgb) ----
__global__ __launch_bounds__(NTHR) void k2c_mfma(
    const float* __restrict__ S, const int* __restrict__ cnt,
    const ushort_t* __restrict__ Wtc, const float* __restrict__ pb2u,
    const float* __restrict__ updb,
    const ushort_t* __restrict__ Wtt, const float* __restrict__ tbgb,
    float* outE)
{
  __shared__ __align__(16) ushort_t A_lds[128*ASTR];
  __shared__ __align__(16) ushort_t B_lds[128*ASTR];
  const int t = threadIdx.x, rowbase = blockIdx.x * BM;
  const int wave = t>>6, lane = t&63, srow = t>>1, sh = t&1;
  const int rr = min(rowbase+srow, N_EDGES-1);
  f32x4 acc1[2][8], acc2[2][8];
#pragma unroll
  for (int i=0;i<2;i++)
#pragma unroll
    for (int j=0;j<8;j++){ acc1[i][j]=(f32x4){0.f,0.f,0.f,0.f}; acc2[i][j]=(f32x4){0.f,0.f,0.f,0.f}; }
  for (int step = 0; step < 2; ++step) {       // phase 1: S @ Wc
    float4 x[8];
    load32<false>(S + (size_t)rr*DIM + step*64 + sh*32, x);
    cvt_store32(x, A_lds + srow*ASTR + sh*32);
    stage_B(Wtc, 128, step*64, B_lds, t);
    __syncthreads();
    mfma_step(A_lds, B_lds, wave, lane, acc1);
    __syncthreads();
  }
  for (int step = 0; step < 2; ++step) {       // phase 2: ef1 @ tbgW
    float4 x[8];
    load32<false>(outE + (size_t)rr*DIM + step*64 + sh*32, x);
    cvt_store32(x, A_lds + srow*ASTR + sh*32);
    stage_B(Wtt, 128, step*64, B_lds, t);
    __syncthreads();
    mfma_step(A_lds, B_lds, wave, lane, acc2);
    __syncthreads();
  }
  const int l15 = lane&15, lhi = lane>>4;
#pragma unroll
  for (int tc=0;tc<8;tc++){
    int c = tc*16 + l15;
    float pu = pb2u[c], ubc = updb[c], tbc = tbgb[c];
#pragma unroll
    for (int tr=0;tr<2;tr++)
#pragma unroll
      for (int reg=0;reg<4;reg++){
        int r = rowbase + wave*32 + tr*16 + lhi*4 + reg;
        if (r < N_EDGES) {
          size_t o = (size_t)r*DIM + c;
          float cf = (float)cnt[r];
          float e3 = n2nf_(acc1[tr][tc][reg] + cf*pu + ubc);
          float g  = sigmoidf_(acc2[tr][tc][reg] + tbc);
          outE[o] = outE[o] + e3 * g;
        }
      }
  }
}

// ---- K3a: msg[dst] += outE row ; deg[dst] += 1 ----
__global__ __launch_bounds__(NTHR) void k3a_msg(
    const float* __restrict__ outE, const int* __restrict__ dst,
    float* __restrict__ msg, float* __restrict__ deg)
{
  int idx = blockIdx.x * NTHR + threadIdx.x;
  int e = idx >> 5;
  if (e < N_EDGES) {
    int c = (idx & 31) << 2;
    int d = dst[e];
    float4 v = *(const float4*)&outE[(size_t)e*DIM + c];
    atomicAdd(&msg[(size_t)d*DIM + c + 0], v.x);
    atomicAdd(&msg[(size_t)d*DIM + c + 1], v.y);
    atomicAdd(&msg[(size_t)d*DIM + c + 2], v.z);
    atomicAdd(&msg[(size_t)d*DIM + c + 3], v.w);
    if ((idx & 31) == 0) atomicAdd(&deg[d], 1.0f);
  }
}

// ---- K3b: H3 = silu([nf, msg/deg] @ node_W1 + b1) (fp32, node-scale) ----
__global__ __launch_bounds__(NTHR) void k3b_node_h(
    const float* __restrict__ nf, const float* __restrict__ msg,
    const float* __restrict__ deg,
    const float* __restrict__ W1, const float* __restrict__ b1,
    float* __restrict__ H3)
{
  __shared__ __align__(16) float As[BK][132];
  __shared__ __align__(16) float Bs[BK][DIM];
  __shared__ float s_rd[BM];
  const int t = threadIdx.x;
  const int rowbase = blockIdx.x * BM;
  if (t < BM) {
    int v = min(rowbase + t, N_NODES-1);
    s_rd[t] = 1.0f / fmaxf(deg[v], 1.0f);
  }
  float acc[8][8];
#pragma unroll
  for (int i=0;i<8;i++)
#pragma unroll
    for (int j=0;j<8;j++) acc[i][j]=0.f;
  const int rr = t >> 3, kk = (t & 7) << 2;
  const int ty8 = (t >> 4) << 3, tx8 = (t & 15) << 3;
  for (int kt = 0; kt < 2*DIM; kt += BK) {
    __syncthreads();
#pragma unroll
    for (int p = 0; p < 4; ++p) {
      int m = p*32 + rr;
      int r = min(rowbase+m, N_NODES-1);
      int c = kt + kk;
      float4 v;
      if (c < DIM) v = *(const float4*)&nf[(size_t)r*DIM + c];
      else {
        v = *(const float4*)&msg[(size_t)r*DIM + (c-DIM)];
        float s = s_rd[m];
        v.x*=s; v.y*=s; v.z*=s; v.w*=s;
      }
      As[kk+0][m]=v.x; As[kk+1][m]=v.y; As[kk+2][m]=v.z; As[kk+3][m]=v.w;
    }
    load_W(W1, kt, 2*DIM, Bs, t);
    __syncthreads();
    tile_mac(As, Bs, ty8, tx8, acc);
  }
#pragma unroll
  for (int i=0;i<8;i++) {
    int r = rowbase + ty8 + i;
    if (r < N_NODES) {
      float o[8];
#pragma unroll
      for (int j=0;j<8;j++) o[j] = siluf_(acc[i][j] + b1[tx8+j]);
      *(float4*)&H3[(size_t)r*DIM + tx8]     = *(float4*)&o[0];
      *(float4*)&H3[(size_t)r*DIM + tx8 + 4] = *(float4*)&o[4];
    }
  }
}

// ---- K3c: outN = nf + H3 @ node_W2 + b2 (fp32, node-scale) ----
__global__ __launch_bounds__(NTHR) void k3c_node_out(
    const float* __restrict__ nf, const float* __restrict__ H3,
    const float* __restrict__ W2, const float* __restrict__ b2,
    float* __restrict__ outN)
{
  __shared__ __align__(16) float As[BK][132];
  __shared__ __align__(16) float Bs[BK][DIM];
  const int t = threadIdx.x;
  const int rowbase = blockIdx.x * BM;
  const int rr = t >> 3, kk = (t & 7) << 2;
  const int ty8 = (t >> 4) << 3, tx8 = (t & 15) << 3;
  float acc[8][8];
#pragma unroll
  for (int i=0;i<8;i++)
#pragma unroll
    for (int j=0;j<8;j++) acc[i][j]=0.f;
  for (int kt = 0; kt < DIM; kt += BK) {
    __syncthreads();
#pragma unroll
    for (int p = 0; p < 4; ++p) {
      int m = p*32 + rr;
      int r = min(rowbase+m, N_NODES-1);
      float4 v = *(const float4*)&H3[(size_t)r*DIM + kt + kk];
      As[kk+0][m]=v.x; As[kk+1][m]=v.y; As[kk+2][m]=v.z; As[kk+3][m]=v.w;
    }
    load_W(W2, kt, DIM, Bs, t);
    __syncthreads();
    tile_mac(As, Bs, ty8, tx8, acc);
  }
#pragma unroll
  for (int i=0;i<8;i++) {
    int r = rowbase + ty8 + i;
    if (r < N_NODES) {
      float o[8];
#pragma unroll
      for (int j=0;j<8;j++)
        o[j] = nf[(size_t)r*DIM + tx8 + j] + acc[i][j] + b2[tx8+j];
      *(float4*)&outN[(size_t)r*DIM + tx8]     = *(float4*)&o[0];
      *(float4*)&outN[(size_t)r*DIM + tx8 + 4] = *(float4*)&o[4];
    }
  }
}

extern "C" void kernel_launch(void* const* d_in, const int* in_sizes, int n_in,
                              void* d_out, int out_size, void* d_ws, size_t ws_size,
                              hipStream_t stream)
{
  const float* nf  = (const float*)d_in[0];
  const float* ef  = (const float*)d_in[1];
  const float* ev  = (const float*)d_in[2];
  const int*  eidx = (const int*)d_in[3];
  const int*  tbe  = (const int*)d_in[5];
  const float* eW1=(const float*)d_in[6],  *eb1=(const float*)d_in[7];
  const float* eW2=(const float*)d_in[8],  *eb2=(const float*)d_in[9];
  const float* gW =(const float*)d_in[10], *gb =(const float*)d_in[11];
  const float* pW1=(const float*)d_in[12], *pb1=(const float*)d_in[13];
  const float* pW2=(const float*)d_in[14], *pb2=(const float*)d_in[15];
  const float* uW =(const float*)d_in[16], *ub =(const float*)d_in[17];
  const float* tW =(const float*)d_in[18], *tb =(const float*)d_in[19];
  const float* nW1=(const float*)d_in[20], *nb1=(const float*)d_in[21];
  const float* nW2=(const float*)d_in[22], *nb2=(const float*)d_in[23];

  const int* src = eidx;
  const int* dst = eidx + N_EDGES;

  float* outN = (float*)d_out;
  float* outE = outN + (size_t)N_NODES*DIM;

  // workspace: [S 256MB][cnt 2MB][Wc 64KB][pb2u 512B][bf16 weight pool ~311KB]
  char* w = (char*)d_ws;
  float* S    = (float*)w;
  int*   cnt  = (int*)(w + (size_t)N_EDGES*DIM*4);
  float* Wc   = (float*)(w + (size_t)N_EDGES*DIM*4 + (size_t)N_EDGES*4);
  float* pb2u = Wc + DIM*DIM;
  ushort_t* Wpool = (ushort_t*)(pb2u + DIM);
  ushort_t* Wt_e1 = Wpool;                 // 128 x 384
  ushort_t* Wt_e2 = Wt_e1 + 128*384;       // 128 x 128
  ushort_t* Wt_g  = Wt_e2 + 128*128;       // 128 x 128
  ushort_t* Wt_p1 = Wt_g  + 128*128;       // 128 x 320 (276 zero-padded)
  ushort_t* Wt_c  = Wt_p1 + 128*320;       // 128 x 128
  ushort_t* Wt_t  = Wt_c  + 128*128;       // 128 x 128
  float* msg  = S;                         // reuse after k2c
  float* deg  = msg + (size_t)N_NODES*DIM;
  float* H3   = deg + N_NODES;

  const int gE = (N_EDGES + BM - 1)/BM;
  const int gT = (N_TRIP  + BM - 1)/BM;
  const int gN = (N_NODES + BM - 1)/BM;

  k0_combine<<<DIM+1, DIM, 0, stream>>>(pW2, pb2, uW, Wc, pb2u);
  w2bf_t<<<(128*384+255)/256, 256, 0, stream>>>(eW1, Wt_e1, 384, 384);
  w2bf_t<<<(128*128+255)/256, 256, 0, stream>>>(eW2, Wt_e2, 128, 128);
  w2bf_t<<<(128*128+255)/256, 256, 0, stream>>>(gW,  Wt_g,  128, 128);
  w2bf_t<<<(128*320+255)/256, 256, 0, stream>>>(pW1, Wt_p1, 276, 320);
  w2bf_t<<<(128*128+255)/256, 256, 0, stream>>>(tW,  Wt_t,  128, 128);
  w2bf_t<<<(128*128+255)/256, 256, 0, stream>>>(Wc,  Wt_c,  128, 128);

  k1a_mfma<<<gE, NTHR, 0, stream>>>(nf, ef, src, dst, Wt_e1, eb1, outE);
  k1b_mfma<<<gE, NTHR, 0, stream>>>(ef, Wt_e2, eb2, Wt_g, gb, outE);
  hipMemsetAsync(S, 0, (size_t)N_EDGES*DIM*4 + (size_t)N_EDGES*4, stream);
  k2b_mfma<<<gT, NTHR, 0, stream>>>(outE, ev, tbe, Wt_p1, pb1, S, cnt);
  k2c_mfma<<<gE, NTHR, 0, stream>>>(S, cnt, Wt_c, pb2u, ub, Wt_t, tb, outE);
  hipMemsetAsync(msg, 0, ((size_t)N_NODES*DIM + N_NODES)*4, stream);
  k3a_msg<<<((size_t)N_EDGES*32 + NTHR-1)/NTHR, NTHR, 0, stream>>>(outE, dst, msg, deg);
  k3b_node_h<<<gN, NTHR, 0, stream>>>(nf, msg, deg, nW1, nb1, H3);
  k3c_node_out<<<gN, NTHR, 0, stream>>>(nf, H3, nW2, nb2, outN);
}